// Round 3
// baseline (341.151 us; speedup 1.0000x reference)
//
#include <hip/hip_runtime.h>

#define NN 40000
#define DD 128
#define EE 640000

// ---------------- init: deg = 1 (self loop), cnt = 0, zero BN sums ----------------
__global__ __launch_bounds__(256) void k_init(float* __restrict__ deg,
                                              int* __restrict__ cnt,
                                              float* __restrict__ sums) {
    int i = blockIdx.x * 256 + threadIdx.x;
    if (i < NN) { deg[i] = 1.0f; cnt[i] = 0; }
    if (i < 256) sums[i] = 0.0f;   // 128 sum + 128 sumsq
}

// ---------------- deg[col] += ew ; cnt[col] += 1 ----------------
__global__ __launch_bounds__(256) void k_deg(const int* __restrict__ ei,
                                             const float* __restrict__ ew,
                                             float* __restrict__ deg,
                                             int* __restrict__ cnt) {
    int e = blockIdx.x * 256 + threadIdx.x;   // E = 2500*256 exactly
    int c = ei[EE + e];
    unsafeAtomicAdd(&deg[c], ew[e]);
    atomicAdd(&cnt[c], 1);
}

// ---------------- exclusive scan of cnt -> off, cursor (single block) ----------------
#define SCAN_CH 40
__global__ __launch_bounds__(1024) void k_scan(const int* __restrict__ cnt,
                                               int* __restrict__ off,
                                               int* __restrict__ cursor) {
    __shared__ int sm[1024];
    int t = threadIdx.x;
    int base = t * SCAN_CH;                   // 1000 threads cover 40000 exactly
    int s = 0;
    if (base < NN) {
#pragma unroll
        for (int i = 0; i < SCAN_CH; ++i) s += cnt[base + i];
    }
    sm[t] = s;
    __syncthreads();
    for (int d = 1; d < 1024; d <<= 1) {      // Hillis-Steele inclusive scan
        int v = (t >= d) ? sm[t - d] : 0;
        __syncthreads();
        sm[t] += v;
        __syncthreads();
    }
    if (base < NN) {
        int run = sm[t] - s;                  // exclusive base for this chunk
#pragma unroll
        for (int i = 0; i < SCAN_CH; ++i) {
            off[base + i] = run;
            cursor[base + i] = run;
            run += cnt[base + i];
        }
    }
    if (t == 1023) off[NN] = sm[1023];        // == EE
}

// ---------------- permute edges into dest-sorted order with fused norm ----------------
__global__ __launch_bounds__(256) void k_permute(const int* __restrict__ ei,
                                                 const float* __restrict__ ew,
                                                 const float* __restrict__ deg,
                                                 int* __restrict__ cursor,
                                                 int2* __restrict__ srn) {
    int e = blockIdx.x * 256 + threadIdx.x;   // 2500 blocks
    int r = ei[e], c = ei[EE + e];
    float nm = ew[e] * rsqrtf(deg[r]) * rsqrtf(deg[c]);
    int pos = atomicAdd(&cursor[c], 1);
    srn[pos] = make_int2(r, __float_as_int(nm));
}

// ---------------- gather: one wave per node, no atomics ----------------
// 4-wide edge unroll: 4 loads issued before first use -> 4 latencies overlap.
__global__ __launch_bounds__(256) void k_gather(const int* __restrict__ off,
                                                const int2* __restrict__ srn,
                                                const float* __restrict__ x,
                                                const float* __restrict__ deg,
                                                float* __restrict__ agg) {
    int gid = blockIdx.x * 256 + threadIdx.x; // 10000 blocks -> 40000 waves
    int node = gid >> 6;
    int lane = gid & 63;
    const float2* x2 = (const float2*)x;
    float inv = 1.0f / deg[node];             // self-loop term: dis^2 * x[i]
    float2 sv = x2[(size_t)node * 64 + lane];
    float2 acc0 = {sv.x * inv, sv.y * inv};
    float2 acc1 = {0.f, 0.f}, acc2 = {0.f, 0.f}, acc3 = {0.f, 0.f};
    int s = off[node], e_end = off[node + 1];
    for (int bse = s; bse < e_end; bse += 64) {
        int ee = bse + lane;
        int2 rv = (ee < e_end) ? srn[ee] : make_int2(0, 0);
        int nb = min(64, e_end - bse);
        int j = 0;
        for (; j + 4 <= nb; j += 4) {
            int r0 = __shfl(rv.x, j);
            int r1 = __shfl(rv.x, j + 1);
            int r2 = __shfl(rv.x, j + 2);
            int r3 = __shfl(rv.x, j + 3);
            float n0 = __shfl(__int_as_float(rv.y), j);
            float n1 = __shfl(__int_as_float(rv.y), j + 1);
            float n2 = __shfl(__int_as_float(rv.y), j + 2);
            float n3 = __shfl(__int_as_float(rv.y), j + 3);
            float2 v0 = x2[(size_t)r0 * 64 + lane];
            float2 v1 = x2[(size_t)r1 * 64 + lane];
            float2 v2 = x2[(size_t)r2 * 64 + lane];
            float2 v3 = x2[(size_t)r3 * 64 + lane];
            acc0.x = fmaf(n0, v0.x, acc0.x); acc0.y = fmaf(n0, v0.y, acc0.y);
            acc1.x = fmaf(n1, v1.x, acc1.x); acc1.y = fmaf(n1, v1.y, acc1.y);
            acc2.x = fmaf(n2, v2.x, acc2.x); acc2.y = fmaf(n2, v2.y, acc2.y);
            acc3.x = fmaf(n3, v3.x, acc3.x); acc3.y = fmaf(n3, v3.y, acc3.y);
        }
        for (; j < nb; ++j) {
            int rr = __shfl(rv.x, j);
            float nm = __shfl(__int_as_float(rv.y), j);
            float2 v = x2[(size_t)rr * 64 + lane];
            acc0.x = fmaf(nm, v.x, acc0.x); acc0.y = fmaf(nm, v.y, acc0.y);
        }
    }
    acc0.x += acc1.x + acc2.x + acc3.x;
    acc0.y += acc1.y + acc2.y + acc3.y;
    ((float2*)agg)[(size_t)node * 64 + lane] = acc0;
}

// ---------------- h = relu(((1-a)*agg + a*x_orig) @ W), 4 rows/thread ----------------
// 256 thr/block, 256 rows/block, 4 threads/row-group (jg) x 32 cols. W in LDS.
__global__ __launch_bounds__(256) void k_matmul(const float* __restrict__ agg,
                                                const float* __restrict__ xorig,
                                                const float* __restrict__ W,
                                                float* __restrict__ out) {
    __shared__ float Wl[DD * DD];             // 64 KB
    int t = threadIdx.x;
    {   // stage W, coalesced float4
        const float4* Wg = (const float4*)W;
        float4* Wl4 = (float4*)Wl;
#pragma unroll
        for (int i = 0; i < 16; ++i) Wl4[i * 256 + t] = Wg[i * 256 + t];
    }
    __syncthreads();

    int rl = t >> 2, jg = t & 3;
    int r0 = blockIdx.x * 256 + rl * 4;       // 157 blocks; NN%4==0 -> all-or-nothing
    bool valid = (r0 + 3) < NN;
    size_t rr = valid ? (size_t)r0 : 0;
    int j0 = jg * 32;
    int jg2 = jg * 2;                         // bank-conflict rotation

    float4 acc[4][8] = {};                    // acc[r][mp] <-> col j0 + ((jg2+mp)&7)*4
    const float* ap = agg + rr * DD;
    const float* bp = xorig + rr * DD;

    for (int k0 = 0; k0 < DD; k0 += 4) {
        float in[4][4];
#pragma unroll
        for (int r = 0; r < 4; ++r) {
            float4 av = *(const float4*)(ap + r * DD + k0);
            float4 bv = *(const float4*)(bp + r * DD + k0);
            in[r][0] = 0.9f * av.x + 0.1f * bv.x;
            in[r][1] = 0.9f * av.y + 0.1f * bv.y;
            in[r][2] = 0.9f * av.z + 0.1f * bv.z;
            in[r][3] = 0.9f * av.w + 0.1f * bv.w;
        }
#pragma unroll
        for (int kk = 0; kk < 4; ++kk) {
            const float* wr = &Wl[(k0 + kk) * DD + j0];
#pragma unroll
            for (int mp = 0; mp < 8; ++mp) {
                float4 w = *(const float4*)(wr + ((jg2 + mp) & 7) * 4);
#pragma unroll
                for (int r = 0; r < 4; ++r) {
                    acc[r][mp].x = fmaf(in[r][kk], w.x, acc[r][mp].x);
                    acc[r][mp].y = fmaf(in[r][kk], w.y, acc[r][mp].y);
                    acc[r][mp].z = fmaf(in[r][kk], w.z, acc[r][mp].z);
                    acc[r][mp].w = fmaf(in[r][kk], w.w, acc[r][mp].w);
                }
            }
        }
    }
    if (valid) {
#pragma unroll
        for (int r = 0; r < 4; ++r) {
            float* orow = out + (rr + r) * DD;
#pragma unroll
            for (int mp = 0; mp < 8; ++mp) {
                int cm = j0 + ((jg2 + mp) & 7) * 4;
                float4 v = acc[r][mp];
                v.x = fmaxf(v.x, 0.0f);
                v.y = fmaxf(v.y, 0.0f);
                v.z = fmaxf(v.z, 0.0f);
                v.w = fmaxf(v.w, 0.0f);
                *(float4*)(orow + cm) = v;
            }
        }
    }
}

// ---------------- BN stats: per-column sum & sumsq ----------------
__global__ __launch_bounds__(256) void k_stats(const float* __restrict__ h,
                                               float* __restrict__ sums) {
    int t = threadIdx.x;
    int tid = blockIdx.x * 256 + t;           // 256 blocks
    int cg = t & 31;                          // float4 column group
    int row0 = tid >> 5;                      // 0..2047
    float4 s = {0, 0, 0, 0}, q = {0, 0, 0, 0};
    for (int r = row0; r < NN; r += 2048) {
        float4 v = *(const float4*)&h[(size_t)r * DD + cg * 4];
        s.x += v.x; s.y += v.y; s.z += v.z; s.w += v.w;
        q.x += v.x * v.x; q.y += v.y * v.y; q.z += v.z * v.z; q.w += v.w * v.w;
    }
    __shared__ float red[256][8];
    red[t][0] = s.x; red[t][1] = s.y; red[t][2] = s.z; red[t][3] = s.w;
    red[t][4] = q.x; red[t][5] = q.y; red[t][6] = q.z; red[t][7] = q.w;
    __syncthreads();
    if (t < 32) {
#pragma unroll
        for (int s8 = 1; s8 < 8; ++s8)
#pragma unroll
            for (int c = 0; c < 8; ++c) red[t][c] += red[t + 32 * s8][c];
        int j = t * 4;
        unsafeAtomicAdd(&sums[j + 0], red[t][0]);
        unsafeAtomicAdd(&sums[j + 1], red[t][1]);
        unsafeAtomicAdd(&sums[j + 2], red[t][2]);
        unsafeAtomicAdd(&sums[j + 3], red[t][3]);
        unsafeAtomicAdd(&sums[DD + j + 0], red[t][4]);
        unsafeAtomicAdd(&sums[DD + j + 1], red[t][5]);
        unsafeAtomicAdd(&sums[DD + j + 2], red[t][6]);
        unsafeAtomicAdd(&sums[DD + j + 3], red[t][7]);
    }
}

// ---------------- BN apply (in place on d_out) ----------------
__global__ __launch_bounds__(256) void k_apply(float* __restrict__ h,
                                               const float* __restrict__ sums,
                                               const float* __restrict__ gamma,
                                               const float* __restrict__ beta) {
    int g = blockIdx.x * 256 + threadIdx.x;   // N*32 threads
    int i = g >> 5, q = g & 31;
    int j = q * 4;
    const float invN = 1.0f / (float)NN;
    float4 sm = *(const float4*)&sums[j];
    float4 sq = *(const float4*)&sums[DD + j];
    float4 gm = *(const float4*)&gamma[j];
    float4 bt = *(const float4*)&beta[j];
    float4 v = *(float4*)&h[(size_t)i * DD + j];
    float m0 = sm.x * invN, m1 = sm.y * invN, m2 = sm.z * invN, m3 = sm.w * invN;
    float i0 = rsqrtf(fmaxf(sq.x * invN - m0 * m0, 0.0f) + 1e-5f);
    float i1 = rsqrtf(fmaxf(sq.y * invN - m1 * m1, 0.0f) + 1e-5f);
    float i2 = rsqrtf(fmaxf(sq.z * invN - m2 * m2, 0.0f) + 1e-5f);
    float i3 = rsqrtf(fmaxf(sq.w * invN - m3 * m3, 0.0f) + 1e-5f);
    v.x = (v.x - m0) * i0 * gm.x + bt.x;
    v.y = (v.y - m1) * i1 * gm.y + bt.y;
    v.z = (v.z - m2) * i2 * gm.z + bt.z;
    v.w = (v.w - m3) * i3 * gm.w + bt.w;
    *(float4*)&h[(size_t)i * DD + j] = v;
}

extern "C" void kernel_launch(void* const* d_in, const int* in_sizes, int n_in,
                              void* d_out, int out_size, void* d_ws, size_t ws_size,
                              hipStream_t stream) {
    const float* x     = (const float*)d_in[0];
    const float* xorig = (const float*)d_in[1];
    const int*   ei    = (const int*)d_in[2];
    const float* ew    = (const float*)d_in[3];
    const float* W     = (const float*)d_in[4];
    const float* gamma = (const float*)d_in[5];
    const float* beta  = (const float*)d_in[6];
    float* out = (float*)d_out;

    // workspace layout (agg first keeps 8B alignment for srn)
    float* ws   = (float*)d_ws;
    float* agg  = ws;                              // N*D floats
    int2*  srn  = (int2*)(agg + (size_t)NN * DD);  // E int2 (row, norm-bits)
    float* deg  = (float*)(srn + EE);              // N floats
    float* sums = deg + NN;                        // 256 floats
    int*   cnt  = (int*)(sums + 256);              // N
    int*   off  = cnt + NN;                        // N+1
    int*   cursor = off + NN + 1;                  // N

    k_init   <<<160,   256, 0, stream>>>(deg, cnt, sums);
    k_deg    <<<2500,  256, 0, stream>>>(ei, ew, deg, cnt);
    k_scan   <<<1,    1024, 0, stream>>>(cnt, off, cursor);
    k_permute<<<2500,  256, 0, stream>>>(ei, ew, deg, cursor, srn);
    k_gather <<<10000, 256, 0, stream>>>(off, srn, x, deg, agg);
    k_matmul <<<157,   256, 0, stream>>>(agg, xorig, W, out);
    k_stats  <<<256,   256, 0, stream>>>(out, sums);
    k_apply  <<<5000,  256, 0, stream>>>(out, sums, gamma, beta);
}

// Round 8
// 284.492 us; speedup vs baseline: 1.1992x; 1.1992x over previous
//
#include <hip/hip_runtime.h>

#define NN 40000
#define DD 128
#define EE 640000

// ---------------- init: cnt = 0, zero BN sums ----------------
__global__ __launch_bounds__(256) void k_init(int* __restrict__ cnt,
                                              float* __restrict__ sums) {
    int i = blockIdx.x * 256 + threadIdx.x;
    if (i < NN) cnt[i] = 0;
    if (i < 256) sums[i] = 0.0f;   // 128 sum + 128 sumsq
}

// ---------------- rank[e] = cnt[col]++  (the ONLY atomic pass) ----------------
__global__ __launch_bounds__(256) void k_rank(const int* __restrict__ ei,
                                              int* __restrict__ cnt,
                                              int* __restrict__ rank) {
    int e = blockIdx.x * 256 + threadIdx.x;   // E = 2500*256 exactly
    int c = ei[EE + e];
    rank[e] = atomicAdd(&cnt[c], 1);
}

// ---------------- exclusive scan of cnt -> off (single block) ----------------
#define SCAN_CH 40
__global__ __launch_bounds__(1024) void k_scan(const int* __restrict__ cnt,
                                               int* __restrict__ off) {
    __shared__ int sm[1024];
    int t = threadIdx.x;
    int base = t * SCAN_CH;                   // 1000 threads cover 40000 exactly
    int s = 0;
    if (base < NN) {
#pragma unroll
        for (int i = 0; i < SCAN_CH; ++i) s += cnt[base + i];
    }
    sm[t] = s;
    __syncthreads();
    for (int d = 1; d < 1024; d <<= 1) {      // Hillis-Steele inclusive scan
        int v = (t >= d) ? sm[t - d] : 0;
        __syncthreads();
        sm[t] += v;
        __syncthreads();
    }
    if (base < NN) {
        int run = sm[t] - s;                  // exclusive base for this chunk
#pragma unroll
        for (int i = 0; i < SCAN_CH; ++i) {
            off[base + i] = run;
            run += cnt[base + i];
        }
    }
    if (t == 1023) off[NN] = sm[1023];        // == EE
}

// ---------------- permute edges into dest-sorted order (NO atomics) ----------------
__global__ __launch_bounds__(256) void k_permute(const int* __restrict__ ei,
                                                 const float* __restrict__ ew,
                                                 const int* __restrict__ rank,
                                                 const int* __restrict__ off,
                                                 int2* __restrict__ srn) {
    int e = blockIdx.x * 256 + threadIdx.x;   // 2500 blocks
    int r = ei[e], c = ei[EE + e];
    int pos = off[c] + rank[e];
    srn[pos] = make_int2(r, __float_as_int(ew[e]));
}

// ---------------- deg from CSR segments: dis = rsqrt(1 + sum ew), wave/node ----------------
__global__ __launch_bounds__(256) void k_degdis(const int* __restrict__ off,
                                                const int2* __restrict__ srn,
                                                float* __restrict__ dis) {
    int gid = blockIdx.x * 256 + threadIdx.x; // 10000 blocks -> 40000 waves
    int node = gid >> 6;
    int lane = gid & 63;
    int s = off[node], e = off[node + 1];
    float v = 0.0f;
    for (int p = s + lane; p < e; p += 64) v += __int_as_float(srn[p].y);
#pragma unroll
    for (int m = 1; m < 64; m <<= 1) v += __shfl_xor(v, m);
    if (lane == 0) dis[node] = rsqrtf(1.0f + v);
}

// ---------------- gather: one wave per node, norm computed on the fly ----------------
// 4-wide edge unroll: 4 independent x-row loads in flight per iter.
__global__ __launch_bounds__(256) void k_gather(const int* __restrict__ off,
                                                const int2* __restrict__ srn,
                                                const float* __restrict__ x,
                                                const float* __restrict__ dis,
                                                float* __restrict__ agg) {
    int gid = blockIdx.x * 256 + threadIdx.x; // 10000 blocks -> 40000 waves
    int node = gid >> 6;
    int lane = gid & 63;
    const float2* x2 = (const float2*)x;
    float dc = dis[node];
    float2 sv = x2[(size_t)node * 64 + lane];
    float2 acc0 = {sv.x * dc, sv.y * dc};     // self term: dc*(dc*x_c) after final scale
    float2 acc1 = {0.f, 0.f}, acc2 = {0.f, 0.f}, acc3 = {0.f, 0.f};
    int s = off[node], e_end = off[node + 1];
    for (int bse = s; bse < e_end; bse += 64) {
        int ee = bse + lane;
        bool act = (ee < e_end);
        int2 rv = act ? srn[ee] : make_int2(0, 0);
        float dl = act ? dis[rv.x] : 0.0f;
        float nmL = __int_as_float(rv.y) * dl;  // ew * dis[row]
        int nb = min(64, e_end - bse);
        int j = 0;
        for (; j + 4 <= nb; j += 4) {
            int r0 = __shfl(rv.x, j);
            int r1 = __shfl(rv.x, j + 1);
            int r2 = __shfl(rv.x, j + 2);
            int r3 = __shfl(rv.x, j + 3);
            float n0 = __shfl(nmL, j);
            float n1 = __shfl(nmL, j + 1);
            float n2 = __shfl(nmL, j + 2);
            float n3 = __shfl(nmL, j + 3);
            float2 v0 = x2[(size_t)r0 * 64 + lane];
            float2 v1 = x2[(size_t)r1 * 64 + lane];
            float2 v2 = x2[(size_t)r2 * 64 + lane];
            float2 v3 = x2[(size_t)r3 * 64 + lane];
            acc0.x = fmaf(n0, v0.x, acc0.x); acc0.y = fmaf(n0, v0.y, acc0.y);
            acc1.x = fmaf(n1, v1.x, acc1.x); acc1.y = fmaf(n1, v1.y, acc1.y);
            acc2.x = fmaf(n2, v2.x, acc2.x); acc2.y = fmaf(n2, v2.y, acc2.y);
            acc3.x = fmaf(n3, v3.x, acc3.x); acc3.y = fmaf(n3, v3.y, acc3.y);
        }
        for (; j < nb; ++j) {
            int rr = __shfl(rv.x, j);
            float nm = __shfl(nmL, j);
            float2 v = x2[(size_t)rr * 64 + lane];
            acc0.x = fmaf(nm, v.x, acc0.x); acc0.y = fmaf(nm, v.y, acc0.y);
        }
    }
    acc0.x = dc * (acc0.x + acc1.x + acc2.x + acc3.x);
    acc0.y = dc * (acc0.y + acc1.y + acc2.y + acc3.y);
    ((float2*)agg)[(size_t)node * 64 + lane] = acc0;
}

// ---------------- h = relu(((1-a)*agg + a*x_orig) @ W), 4 rows/thread ----------------
__global__ __launch_bounds__(256) void k_matmul(const float* __restrict__ agg,
                                                const float* __restrict__ xorig,
                                                const float* __restrict__ W,
                                                float* __restrict__ out) {
    __shared__ float Wl[DD * DD];             // 64 KB
    int t = threadIdx.x;
    {   // stage W, coalesced float4
        const float4* Wg = (const float4*)W;
        float4* Wl4 = (float4*)Wl;
#pragma unroll
        for (int i = 0; i < 16; ++i) Wl4[i * 256 + t] = Wg[i * 256 + t];
    }
    __syncthreads();

    int rl = t >> 2, jg = t & 3;
    int r0 = blockIdx.x * 256 + rl * 4;       // 157 blocks
    bool valid = (r0 + 3) < NN;
    size_t rr = valid ? (size_t)r0 : 0;
    int j0 = jg * 32;
    int jg2 = jg * 2;                         // bank-conflict rotation

    float4 acc[4][8] = {};                    // acc[r][mp] <-> col j0 + ((jg2+mp)&7)*4
    const float* ap = agg + rr * DD;
    const float* bp = xorig + rr * DD;

    for (int k0 = 0; k0 < DD; k0 += 4) {
        float in[4][4];
#pragma unroll
        for (int r = 0; r < 4; ++r) {
            float4 av = *(const float4*)(ap + r * DD + k0);
            float4 bv = *(const float4*)(bp + r * DD + k0);
            in[r][0] = 0.9f * av.x + 0.1f * bv.x;
            in[r][1] = 0.9f * av.y + 0.1f * bv.y;
            in[r][2] = 0.9f * av.z + 0.1f * bv.z;
            in[r][3] = 0.9f * av.w + 0.1f * bv.w;
        }
#pragma unroll
        for (int kk = 0; kk < 4; ++kk) {
            const float* wr = &Wl[(k0 + kk) * DD + j0];
#pragma unroll
            for (int mp = 0; mp < 8; ++mp) {
                float4 w = *(const float4*)(wr + ((jg2 + mp) & 7) * 4);
#pragma unroll
                for (int r = 0; r < 4; ++r) {
                    acc[r][mp].x = fmaf(in[r][kk], w.x, acc[r][mp].x);
                    acc[r][mp].y = fmaf(in[r][kk], w.y, acc[r][mp].y);
                    acc[r][mp].z = fmaf(in[r][kk], w.z, acc[r][mp].z);
                    acc[r][mp].w = fmaf(in[r][kk], w.w, acc[r][mp].w);
                }
            }
        }
    }
    if (valid) {
#pragma unroll
        for (int r = 0; r < 4; ++r) {
            float* orow = out + (rr + r) * DD;
#pragma unroll
            for (int mp = 0; mp < 8; ++mp) {
                int cm = j0 + ((jg2 + mp) & 7) * 4;
                float4 v = acc[r][mp];
                v.x = fmaxf(v.x, 0.0f);
                v.y = fmaxf(v.y, 0.0f);
                v.z = fmaxf(v.z, 0.0f);
                v.w = fmaxf(v.w, 0.0f);
                *(float4*)(orow + cm) = v;
            }
        }
    }
}

// ---------------- BN stats: per-column sum & sumsq ----------------
__global__ __launch_bounds__(256) void k_stats(const float* __restrict__ h,
                                               float* __restrict__ sums) {
    int t = threadIdx.x;
    int tid = blockIdx.x * 256 + t;           // 256 blocks
    int cg = t & 31;                          // float4 column group
    int row0 = tid >> 5;                      // 0..2047
    float4 s = {0, 0, 0, 0}, q = {0, 0, 0, 0};
    for (int r = row0; r < NN; r += 2048) {
        float4 v = *(const float4*)&h[(size_t)r * DD + cg * 4];
        s.x += v.x; s.y += v.y; s.z += v.z; s.w += v.w;
        q.x += v.x * v.x; q.y += v.y * v.y; q.z += v.z * v.z; q.w += v.w * v.w;
    }
    __shared__ float red[256][8];
    red[t][0] = s.x; red[t][1] = s.y; red[t][2] = s.z; red[t][3] = s.w;
    red[t][4] = q.x; red[t][5] = q.y; red[t][6] = q.z; red[t][7] = q.w;
    __syncthreads();
    if (t < 32) {
#pragma unroll
        for (int s8 = 1; s8 < 8; ++s8)
#pragma unroll
            for (int c = 0; c < 8; ++c) red[t][c] += red[t + 32 * s8][c];
        int j = t * 4;
        unsafeAtomicAdd(&sums[j + 0], red[t][0]);
        unsafeAtomicAdd(&sums[j + 1], red[t][1]);
        unsafeAtomicAdd(&sums[j + 2], red[t][2]);
        unsafeAtomicAdd(&sums[j + 3], red[t][3]);
        unsafeAtomicAdd(&sums[DD + j + 0], red[t][4]);
        unsafeAtomicAdd(&sums[DD + j + 1], red[t][5]);
        unsafeAtomicAdd(&sums[DD + j + 2], red[t][6]);
        unsafeAtomicAdd(&sums[DD + j + 3], red[t][7]);
    }
}

// ---------------- BN apply (in place on d_out) ----------------
__global__ __launch_bounds__(256) void k_apply(float* __restrict__ h,
                                               const float* __restrict__ sums,
                                               const float* __restrict__ gamma,
                                               const float* __restrict__ beta) {
    int g = blockIdx.x * 256 + threadIdx.x;   // N*32 threads
    int i = g >> 5, q = g & 31;
    int j = q * 4;
    const float invN = 1.0f / (float)NN;
    float4 sm = *(const float4*)&sums[j];
    float4 sq = *(const float4*)&sums[DD + j];
    float4 gm = *(const float4*)&gamma[j];
    float4 bt = *(const float4*)&beta[j];
    float4 v = *(float4*)&h[(size_t)i * DD + j];
    float m0 = sm.x * invN, m1 = sm.y * invN, m2 = sm.z * invN, m3 = sm.w * invN;
    float i0 = rsqrtf(fmaxf(sq.x * invN - m0 * m0, 0.0f) + 1e-5f);
    float i1 = rsqrtf(fmaxf(sq.y * invN - m1 * m1, 0.0f) + 1e-5f);
    float i2 = rsqrtf(fmaxf(sq.z * invN - m2 * m2, 0.0f) + 1e-5f);
    float i3 = rsqrtf(fmaxf(sq.w * invN - m3 * m3, 0.0f) + 1e-5f);
    v.x = (v.x - m0) * i0 * gm.x + bt.x;
    v.y = (v.y - m1) * i1 * gm.y + bt.y;
    v.z = (v.z - m2) * i2 * gm.z + bt.z;
    v.w = (v.w - m3) * i3 * gm.w + bt.w;
    *(float4*)&h[(size_t)i * DD + j] = v;
}

extern "C" void kernel_launch(void* const* d_in, const int* in_sizes, int n_in,
                              void* d_out, int out_size, void* d_ws, size_t ws_size,
                              hipStream_t stream) {
    const float* x     = (const float*)d_in[0];
    const float* xorig = (const float*)d_in[1];
    const int*   ei    = (const int*)d_in[2];
    const float* ew    = (const float*)d_in[3];
    const float* W     = (const float*)d_in[4];
    const float* gamma = (const float*)d_in[5];
    const float* beta  = (const float*)d_in[6];
    float* out = (float*)d_out;

    // workspace layout (agg first keeps 8B alignment for srn)
    float* ws   = (float*)d_ws;
    float* agg  = ws;                              // N*D floats
    int2*  srn  = (int2*)(agg + (size_t)NN * DD);  // E int2 (row, ew-bits)
    float* dis  = (float*)(srn + EE);              // N floats
    float* sums = dis + NN;                        // 256 floats
    int*   cnt  = (int*)(sums + 256);              // N
    int*   off  = cnt + NN;                        // N+1
    int*   rank = off + NN + 1;                    // E

    k_init   <<<160,   256, 0, stream>>>(cnt, sums);
    k_rank   <<<2500,  256, 0, stream>>>(ei, cnt, rank);
    k_scan   <<<1,    1024, 0, stream>>>(cnt, off);
    k_permute<<<2500,  256, 0, stream>>>(ei, ew, rank, off, srn);
    k_degdis <<<10000, 256, 0, stream>>>(off, srn, dis);
    k_gather <<<10000, 256, 0, stream>>>(off, srn, x, dis, agg);
    k_matmul <<<157,   256, 0, stream>>>(agg, xorig, W, out);
    k_stats  <<<256,   256, 0, stream>>>(out, sums);
    k_apply  <<<5000,  256, 0, stream>>>(out, sums, gamma, beta);
}